// Round 1
// baseline (2470.114 us; speedup 1.0000x reference)
//
#include <hip/hip_runtime.h>

// Problem constants (from reference)
#define PN 50000
#define PE 1600000
#define PB 4096

// ---------------- workspace layout (in floats) ----------------
// 0      : bn_sum[64] | bn_sumsq[64] | scale[64] | offset[64]   (256)
// 256    : tmpM (192*128)
// 24832  : M (192*192)
// 61696  : deg_up/inv_up (N)
// 111696 : deg_dn/inv_dn (N)
// 161696 : h    (N*192)
// then   : proj (N*192)   [up | dn | bi]
// then   : acc  (N*128)   [acc_up (N*64) | acc_dn (N*64)]
static constexpr size_t OFF_BN   = 0;
static constexpr size_t OFF_TMPM = 256;
static constexpr size_t OFF_M    = OFF_TMPM + 192 * 128;
static constexpr size_t OFF_DEGU = OFF_M + 192 * 192;
static constexpr size_t OFF_DEGD = OFF_DEGU + PN;
static constexpr size_t OFF_H    = OFF_DEGD + PN;
static constexpr size_t OFF_PROJ = OFF_H + (size_t)PN * 192;
static constexpr size_t OFF_ACC  = OFF_PROJ + (size_t)PN * 192;

// ---------------- batchnorm stats ----------------
__global__ __launch_bounds__(256) void bn_stats_kernel(const float* __restrict__ x,
                                                       float* __restrict__ sums, int N) {
    __shared__ float ls[256], ls2[256];
    int col = threadIdx.x & 63;
    int rstart = blockIdx.x * 4 + (threadIdx.x >> 6);
    float s = 0.f, s2 = 0.f;
    for (int r = rstart; r < N; r += gridDim.x * 4) {
        float v = x[(size_t)r * 64 + col];
        s += v; s2 += v * v;
    }
    ls[threadIdx.x] = s; ls2[threadIdx.x] = s2;
    __syncthreads();
    if (threadIdx.x < 64) {
        s  = ls[threadIdx.x]  + ls[threadIdx.x + 64]  + ls[threadIdx.x + 128]  + ls[threadIdx.x + 192];
        s2 = ls2[threadIdx.x] + ls2[threadIdx.x + 64] + ls2[threadIdx.x + 128] + ls2[threadIdx.x + 192];
        atomicAdd(&sums[col], s);
        atomicAdd(&sums[64 + col], s2);
    }
}

__global__ __launch_bounds__(64) void bn_finalize_kernel(const float* __restrict__ gamma,
                                                         const float* __restrict__ beta,
                                                         float* __restrict__ bn, int N) {
    int c = threadIdx.x;
    float mean = bn[c] / (float)N;
    float var = bn[64 + c] / (float)N - mean * mean;
    float sc = gamma[c] * rsqrtf(var + 1e-5f);
    bn[128 + c] = sc;              // scale
    bn[192 + c] = beta[c] - mean * sc;  // offset
}

__global__ __launch_bounds__(256) void apply_bn_kernel(const float* __restrict__ x,
                                                       const float* __restrict__ bn,
                                                       float* __restrict__ h, int N) {
    int idx = blockIdx.x * 256 + threadIdx.x;
    if (idx >= N * 64) return;
    int n = idx >> 6, f = idx & 63;
    h[(size_t)n * 192 + f] = x[idx] * bn[128 + f] + bn[192 + f];
}

// ---------------- degrees ----------------
__global__ __launch_bounds__(256) void deg_kernel(const int* __restrict__ ei,
                                                  float* __restrict__ deg_up,
                                                  float* __restrict__ deg_dn, int E) {
    int e = blockIdx.x * 256 + threadIdx.x;
    if (e >= E) return;
    atomicAdd(&deg_up[ei[E + e]], 1.0f);  // col in-degree
    atomicAdd(&deg_dn[ei[e]], 1.0f);      // row out-degree
}

__global__ __launch_bounds__(256) void invdeg_kernel(float* __restrict__ deg_up,
                                                     float* __restrict__ deg_dn, int N) {
    int i = blockIdx.x * 256 + threadIdx.x;
    if (i >= N) return;
    deg_up[i] = 1.0f / fmaxf(deg_up[i], 1.0f);
    deg_dn[i] = 1.0f / fmaxf(deg_dn[i], 1.0f);
}

// ---------------- GEMM: C[N,192] (ld 192) = A[N,K] (ld 192) @ {Wu|Wd|Wb}[K,64] ----------------
// block 256 threads, tile 64 rows x 64 cols, BK=64, 4x4 microtile
__global__ __launch_bounds__(256) void gemm_kernel(const float* __restrict__ A,
                                                   const float* __restrict__ Wu,
                                                   const float* __restrict__ Wd,
                                                   const float* __restrict__ Wb,
                                                   float* __restrict__ C, int nrows, int K) {
    __shared__ float As[64][66];  // [k][r], pad 66 -> 4-way write conflict only
    __shared__ float Ws[64][64];  // [k][c]
    const int cb = blockIdx.y;
    const float* W = (cb == 0) ? Wu : (cb == 1 ? Wd : Wb);
    const int rowBase = blockIdx.x * 64;
    const int tid = threadIdx.x;
    const int tr = tid >> 4, tc = tid & 15;
    float acc[4][4] = {};

    for (int k0 = 0; k0 < K; k0 += 64) {
        // stage A (transposed) and W
        int ka = tid & 63;
        int rb = tid >> 6;
#pragma unroll
        for (int i = 0; i < 16; ++i) {
            int r = rb + 4 * i;
            int gr = rowBase + r;
            float v = 0.f;
            if (gr < nrows) v = A[(size_t)gr * 192 + k0 + ka];
            As[ka][r] = v;
            Ws[r][ka] = W[(size_t)(k0 + r) * 64 + ka];
        }
        __syncthreads();
#pragma unroll 8
        for (int k = 0; k < 64; ++k) {
            float4 w = *(const float4*)&Ws[k][tc * 4];
            float a0 = As[k][tr * 4 + 0];
            float a1 = As[k][tr * 4 + 1];
            float a2 = As[k][tr * 4 + 2];
            float a3 = As[k][tr * 4 + 3];
            acc[0][0] += a0 * w.x; acc[0][1] += a0 * w.y; acc[0][2] += a0 * w.z; acc[0][3] += a0 * w.w;
            acc[1][0] += a1 * w.x; acc[1][1] += a1 * w.y; acc[1][2] += a1 * w.z; acc[1][3] += a1 * w.w;
            acc[2][0] += a2 * w.x; acc[2][1] += a2 * w.y; acc[2][2] += a2 * w.z; acc[2][3] += a2 * w.w;
            acc[3][0] += a3 * w.x; acc[3][1] += a3 * w.y; acc[3][2] += a3 * w.z; acc[3][3] += a3 * w.w;
        }
        __syncthreads();
    }
#pragma unroll
    for (int i = 0; i < 4; ++i) {
        int gr = rowBase + tr * 4 + i;
        if (gr < nrows) {
            float4 v = make_float4(acc[i][0], acc[i][1], acc[i][2], acc[i][3]);
            *(float4*)&C[(size_t)gr * 192 + cb * 64 + tc * 4] = v;
        }
    }
}

// ---------------- edge scatter (atomic) ----------------
// proj: [up(0:64) | dn(64:128) | bi(128:192)], acc: [acc_up (N*64) | acc_dn (N*64)]
__global__ __launch_bounds__(256) void scatter_kernel(const float* __restrict__ proj,
                                                      const int* __restrict__ ei,
                                                      float* __restrict__ acc, int E, int N) {
    int e = blockIdx.x * 4 + (threadIdx.x >> 6);
    int f = threadIdx.x & 63;
    if (e >= E) return;
    int r = ei[e];
    int c = ei[E + e];
    atomicAdd(&acc[(size_t)c * 64 + f], proj[(size_t)r * 192 + f]);
    atomicAdd(&acc[(size_t)(N + r) * 64 + f], proj[(size_t)c * 192 + 64 + f]);
}

// ---------------- combine: divide by deg, concat, L2-normalize, leaky ----------------
__global__ __launch_bounds__(256) void combine_kernel(const float* __restrict__ acc,
                                                      const float* __restrict__ proj,
                                                      const float* __restrict__ inv_up,
                                                      const float* __restrict__ inv_dn,
                                                      float* __restrict__ h, int N) {
    int n = blockIdx.x * 4 + (threadIdx.x >> 6);
    int lane = threadIdx.x & 63;
    if (n >= N) return;
    float au = acc[(size_t)n * 64 + lane] * inv_up[n];
    float ad = acc[(size_t)(N + n) * 64 + lane] * inv_dn[n];
    float bi = proj[(size_t)n * 192 + 128 + lane];
    float ss = au * au + ad * ad + bi * bi;
#pragma unroll
    for (int off = 32; off; off >>= 1) ss += __shfl_xor(ss, off);
    float r = 1.0f / fmaxf(sqrtf(ss), 1e-12f);
    au *= r; ad *= r; bi *= r;
    au = au >= 0.f ? au : 0.1f * au;
    ad = ad >= 0.f ? ad : 0.1f * ad;
    bi = bi >= 0.f ? bi : 0.1f * bi;
    h[(size_t)n * 192 + lane] = au;
    h[(size_t)n * 192 + 64 + lane] = ad;
    h[(size_t)n * 192 + 128 + lane] = bi;
}

// ---------------- decoder ----------------
__global__ __launch_bounds__(128) void m1_kernel(const float* __restrict__ P1,
                                                 const float* __restrict__ P2,
                                                 float* __restrict__ tmpM) {
    int i = blockIdx.x, c = threadIdx.x;
    float s = 0.f;
    for (int k = 0; k < 128; ++k) s += P1[i * 128 + k] * P2[k * 128 + c];
    tmpM[i * 128 + c] = s;
}

__global__ __launch_bounds__(192) void m2_kernel(const float* __restrict__ tmpM,
                                                 const float* __restrict__ P1,
                                                 float* __restrict__ M) {
    __shared__ float trow[128];
    int i = blockIdx.x, j = threadIdx.x;
    if (j < 128) trow[j] = tmpM[i * 128 + j];
    __syncthreads();
    float s = 0.f;
    for (int k = 0; k < 128; ++k) s += trow[k] * P1[j * 128 + k];
    M[i * 192 + j] = s;
}

// 8 pairs per block of 192 threads
__global__ __launch_bounds__(192) void decode_kernel(const float* __restrict__ h,
                                                     const int* __restrict__ di,
                                                     const float* __restrict__ M,
                                                     float* __restrict__ out) {
    __shared__ alignas(16) float bvs[8][192];
    __shared__ float red[3][8];
    int pb = blockIdx.x * 8;
    int i = threadIdx.x;
#pragma unroll
    for (int p = 0; p < 8; ++p) {
        int nb = di[(pb + p) * 2 + 1] - 1;
        bvs[p][i] = h[(size_t)nb * 192 + i];
    }
    __syncthreads();
    float t[8] = {};
    const float4* M4 = (const float4*)(M + (size_t)i * 192);
    for (int j4 = 0; j4 < 48; ++j4) {
        float4 m = M4[j4];
#pragma unroll
        for (int p = 0; p < 8; ++p) {
            float4 b = *(const float4*)&bvs[p][j4 * 4];
            t[p] += m.x * b.x + m.y * b.y + m.z * b.z + m.w * b.w;
        }
    }
    int wid = i >> 6, lane = i & 63;
#pragma unroll
    for (int p = 0; p < 8; ++p) {
        int na = di[(pb + p) * 2] - 1;
        float v = h[(size_t)na * 192 + i] * t[p];
#pragma unroll
        for (int off = 32; off; off >>= 1) v += __shfl_xor(v, off);
        if (lane == 0) red[wid][p] = v;
    }
    __syncthreads();
    if (i < 8) out[pb + i] = red[0][i] + red[1][i] + red[2][i];
}

extern "C" void kernel_launch(void* const* d_in, const int* in_sizes, int n_in,
                              void* d_out, int out_size, void* d_ws, size_t ws_size,
                              hipStream_t stream) {
    const float* x     = (const float*)d_in[0];
    const int*   ei    = (const int*)d_in[1];
    const int*   di    = (const int*)d_in[2];
    const float* gamma = (const float*)d_in[3];
    const float* beta  = (const float*)d_in[4];
    const float* Wu[3] = {(const float*)d_in[5], (const float*)d_in[8],  (const float*)d_in[11]};
    const float* Wd[3] = {(const float*)d_in[6], (const float*)d_in[9],  (const float*)d_in[12]};
    const float* Wb[3] = {(const float*)d_in[7], (const float*)d_in[10], (const float*)d_in[13]};
    const float* P1    = (const float*)d_in[14];
    const float* P2    = (const float*)d_in[15];
    float* out = (float*)d_out;
    float* ws  = (float*)d_ws;

    float* bn     = ws + OFF_BN;
    float* tmpM   = ws + OFF_TMPM;
    float* M      = ws + OFF_M;
    float* deg_up = ws + OFF_DEGU;
    float* deg_dn = ws + OFF_DEGD;
    float* h      = ws + OFF_H;
    float* proj   = ws + OFF_PROJ;
    float* acc    = ws + OFF_ACC;

    // zero bn sums + degree counters
    hipMemsetAsync(bn, 0, 128 * sizeof(float), stream);
    hipMemsetAsync(deg_up, 0, 2 * PN * sizeof(float), stream);

    bn_stats_kernel<<<200, 256, 0, stream>>>(x, bn, PN);
    bn_finalize_kernel<<<1, 64, 0, stream>>>(gamma, beta, bn, PN);
    apply_bn_kernel<<<(PN * 64 + 255) / 256, 256, 0, stream>>>(x, bn, h, PN);

    deg_kernel<<<(PE + 255) / 256, 256, 0, stream>>>(ei, deg_up, deg_dn, PE);
    invdeg_kernel<<<(PN + 255) / 256, 256, 0, stream>>>(deg_up, deg_dn, PN);

    for (int l = 0; l < 3; ++l) {
        int K = (l == 0) ? 64 : 192;
        dim3 ggrid((PN + 63) / 64, 3);
        gemm_kernel<<<ggrid, 256, 0, stream>>>(h, Wu[l], Wd[l], Wb[l], proj, PN, K);
        hipMemsetAsync(acc, 0, (size_t)PN * 128 * sizeof(float), stream);
        scatter_kernel<<<(PE + 3) / 4, 256, 0, stream>>>(proj, ei, acc, PE, PN);
        combine_kernel<<<(PN + 3) / 4, 256, 0, stream>>>(acc, proj, deg_up, deg_dn, h, PN);
    }

    m1_kernel<<<192, 128, 0, stream>>>(P1, P2, tmpM);
    m2_kernel<<<192, 192, 0, stream>>>(tmpM, P1, M);
    decode_kernel<<<PB / 8, 192, 0, stream>>>(h, di, M, out);
}

// Round 2
// 1192.377 us; speedup vs baseline: 2.0716x; 2.0716x over previous
//
#include <hip/hip_runtime.h>

#define PN 50000
#define PE 1600000
#define PB 4096

// ---------------- workspace layout (in 4-byte words) ----------------
static constexpr size_t OFF_BN   = 0;                        // 256 f
static constexpr size_t OFF_TMPM = 256;                      // 192*128 f
static constexpr size_t OFF_M    = OFF_TMPM + 192 * 128;     // 192*192 f
static constexpr size_t OFF_INVU = OFF_M + 192 * 192;        // N f
static constexpr size_t OFF_INVD = OFF_INVU + PN;            // N f
static constexpr size_t OFF_DEGU = OFF_INVD + PN;            // N int  (zeroed, contiguous 4N block)
static constexpr size_t OFF_DEGD = OFF_DEGU + PN;            // N int
static constexpr size_t OFF_CURU = OFF_DEGD + PN;            // N int
static constexpr size_t OFF_CURD = OFF_CURU + PN;            // N int
static constexpr size_t OFF_OFFU = OFF_CURD + PN;            // N+1 int
static constexpr size_t OFF_OFFD = OFF_OFFU + PN + 1;        // N+1 int
static constexpr size_t OFF_IDXU = OFF_OFFD + PN + 1;        // E int
static constexpr size_t OFF_IDXD = OFF_IDXU + PE;            // E int
static constexpr size_t OFF_H    = OFF_IDXD + PE;            // N*192 f
static constexpr size_t OFF_PROJ = OFF_H + (size_t)PN * 192; // N*192 f

// ---------------- batchnorm ----------------
__global__ __launch_bounds__(256) void bn_stats_kernel(const float* __restrict__ x,
                                                       float* __restrict__ sums, int N) {
    __shared__ float ls[256], ls2[256];
    int col = threadIdx.x & 63;
    int rstart = blockIdx.x * 4 + (threadIdx.x >> 6);
    float s = 0.f, s2 = 0.f;
    for (int r = rstart; r < N; r += gridDim.x * 4) {
        float v = x[(size_t)r * 64 + col];
        s += v; s2 += v * v;
    }
    ls[threadIdx.x] = s; ls2[threadIdx.x] = s2;
    __syncthreads();
    if (threadIdx.x < 64) {
        s  = ls[threadIdx.x]  + ls[threadIdx.x + 64]  + ls[threadIdx.x + 128]  + ls[threadIdx.x + 192];
        s2 = ls2[threadIdx.x] + ls2[threadIdx.x + 64] + ls2[threadIdx.x + 128] + ls2[threadIdx.x + 192];
        atomicAdd(&sums[col], s);
        atomicAdd(&sums[64 + col], s2);
    }
}

__global__ __launch_bounds__(64) void bn_finalize_kernel(const float* __restrict__ gamma,
                                                         const float* __restrict__ beta,
                                                         float* __restrict__ bn, int N) {
    int c = threadIdx.x;
    float mean = bn[c] / (float)N;
    float var = bn[64 + c] / (float)N - mean * mean;
    float sc = gamma[c] * rsqrtf(var + 1e-5f);
    bn[128 + c] = sc;
    bn[192 + c] = beta[c] - mean * sc;
}

__global__ __launch_bounds__(256) void apply_bn_kernel(const float* __restrict__ x,
                                                       const float* __restrict__ bn,
                                                       float* __restrict__ h, int N) {
    int idx = blockIdx.x * 256 + threadIdx.x;
    if (idx >= N * 64) return;
    int n = idx >> 6, f = idx & 63;
    h[(size_t)n * 192 + f] = x[idx] * bn[128 + f] + bn[192 + f];
}

// ---------------- CSR build ----------------
__global__ __launch_bounds__(256) void deg_kernel(const int* __restrict__ ei,
                                                  int* __restrict__ degu,
                                                  int* __restrict__ degd, int E) {
    int e = blockIdx.x * 256 + threadIdx.x;
    if (e >= E) return;
    atomicAdd(&degu[ei[E + e]], 1);  // in-degree of col
    atomicAdd(&degd[ei[e]], 1);      // out-degree of row
}

__global__ __launch_bounds__(256) void invdeg_kernel(const int* __restrict__ degu,
                                                     const int* __restrict__ degd,
                                                     float* __restrict__ invu,
                                                     float* __restrict__ invd, int N) {
    int i = blockIdx.x * 256 + threadIdx.x;
    if (i >= N) return;
    invu[i] = 1.0f / (float)max(degu[i], 1);
    invd[i] = 1.0f / (float)max(degd[i], 1);
}

// single-block exclusive prefix sum of both degree arrays
__global__ __launch_bounds__(1024) void scan_kernel(const int* __restrict__ degu,
                                                    const int* __restrict__ degd,
                                                    int* __restrict__ offu,
                                                    int* __restrict__ offd, int N) {
    __shared__ int wsum[17];
    int tid = threadIdx.x, lane = tid & 63, wid = tid >> 6;
    for (int a = 0; a < 2; ++a) {
        const int* deg = a ? degd : degu;
        int* off = a ? offd : offu;
        int run = 0;
        for (int base = 0; base < N; base += 1024) {
            int idx = base + tid;
            int v = (idx < N) ? deg[idx] : 0;
            int inc = v;
#pragma unroll
            for (int d = 1; d < 64; d <<= 1) {
                int t = __shfl_up(inc, d);
                if (lane >= d) inc += t;
            }
            if (lane == 63) wsum[wid] = inc;
            __syncthreads();
            if (tid == 0) {
                int r2 = 0;
#pragma unroll
                for (int i = 0; i < 16; ++i) { int t = wsum[i]; wsum[i] = r2; r2 += t; }
                wsum[16] = r2;
            }
            __syncthreads();
            if (idx < N) off[idx] = run + wsum[wid] + inc - v;
            run += wsum[16];
            __syncthreads();
        }
        if (tid == 0) off[N] = run;
        __syncthreads();
    }
}

__global__ __launch_bounds__(256) void fill_kernel(const int* __restrict__ ei,
                                                   const int* __restrict__ offu,
                                                   const int* __restrict__ offd,
                                                   int* __restrict__ curu,
                                                   int* __restrict__ curd,
                                                   int* __restrict__ idxu,
                                                   int* __restrict__ idxd, int E) {
    int e = blockIdx.x * 256 + threadIdx.x;
    if (e >= E) return;
    int r = ei[e], c = ei[E + e];
    int p = atomicAdd(&curu[c], 1);
    idxu[offu[c] + p] = r;
    int q = atomicAdd(&curd[r], 1);
    idxd[offd[r] + q] = c;
}

// ---------------- GEMM: C[N,192](ld192) = A[N,K](ld192) @ {Wu|Wd|Wb}[K,64] ----------------
__global__ __launch_bounds__(256) void gemm_kernel(const float* __restrict__ A,
                                                   const float* __restrict__ Wu,
                                                   const float* __restrict__ Wd,
                                                   const float* __restrict__ Wb,
                                                   float* __restrict__ C, int nrows, int K) {
    __shared__ float As[64][66];
    __shared__ float Ws[64][64];
    const int cb = blockIdx.y;
    const float* W = (cb == 0) ? Wu : (cb == 1 ? Wd : Wb);
    const int rowBase = blockIdx.x * 64;
    const int tid = threadIdx.x;
    const int tr = tid >> 4, tc = tid & 15;
    float acc[4][4] = {};

    for (int k0 = 0; k0 < K; k0 += 64) {
        int ka = tid & 63;
        int rb = tid >> 6;
#pragma unroll
        for (int i = 0; i < 16; ++i) {
            int r = rb + 4 * i;
            int gr = rowBase + r;
            float v = 0.f;
            if (gr < nrows) v = A[(size_t)gr * 192 + k0 + ka];
            As[ka][r] = v;
            Ws[r][ka] = W[(size_t)(k0 + r) * 64 + ka];
        }
        __syncthreads();
#pragma unroll 8
        for (int k = 0; k < 64; ++k) {
            float4 w = *(const float4*)&Ws[k][tc * 4];
            float a0 = As[k][tr * 4 + 0];
            float a1 = As[k][tr * 4 + 1];
            float a2 = As[k][tr * 4 + 2];
            float a3 = As[k][tr * 4 + 3];
            acc[0][0] += a0 * w.x; acc[0][1] += a0 * w.y; acc[0][2] += a0 * w.z; acc[0][3] += a0 * w.w;
            acc[1][0] += a1 * w.x; acc[1][1] += a1 * w.y; acc[1][2] += a1 * w.z; acc[1][3] += a1 * w.w;
            acc[2][0] += a2 * w.x; acc[2][1] += a2 * w.y; acc[2][2] += a2 * w.z; acc[2][3] += a2 * w.w;
            acc[3][0] += a3 * w.x; acc[3][1] += a3 * w.y; acc[3][2] += a3 * w.z; acc[3][3] += a3 * w.w;
        }
        __syncthreads();
    }
#pragma unroll
    for (int i = 0; i < 4; ++i) {
        int gr = rowBase + tr * 4 + i;
        if (gr < nrows) {
            float4 v = make_float4(acc[i][0], acc[i][1], acc[i][2], acc[i][3]);
            *(float4*)&C[(size_t)gr * 192 + cb * 64 + tc * 4] = v;
        }
    }
}

// ---------------- fused gather + divide + L2-normalize + leaky ----------------
// one wave per node; lane = feature
__global__ __launch_bounds__(256) void gather_kernel(const float* __restrict__ proj,
                                                     const int* __restrict__ offu,
                                                     const int* __restrict__ idxu,
                                                     const int* __restrict__ offd,
                                                     const int* __restrict__ idxd,
                                                     const float* __restrict__ invu,
                                                     const float* __restrict__ invd,
                                                     float* __restrict__ h, int N) {
    int n = blockIdx.x * 4 + (threadIdx.x >> 6);
    int lane = threadIdx.x & 63;
    if (n >= N) return;
    float au = 0.f, ad = 0.f;
    {
        int s = offu[n], e = offu[n + 1], i = s;
        for (; i + 4 <= e; i += 4) {
            int s0 = idxu[i], s1 = idxu[i + 1], s2 = idxu[i + 2], s3 = idxu[i + 3];
            float v0 = proj[(size_t)s0 * 192 + lane];
            float v1 = proj[(size_t)s1 * 192 + lane];
            float v2 = proj[(size_t)s2 * 192 + lane];
            float v3 = proj[(size_t)s3 * 192 + lane];
            au += (v0 + v1) + (v2 + v3);
        }
        for (; i < e; ++i) au += proj[(size_t)idxu[i] * 192 + lane];
    }
    {
        int s = offd[n], e = offd[n + 1], i = s;
        for (; i + 4 <= e; i += 4) {
            int s0 = idxd[i], s1 = idxd[i + 1], s2 = idxd[i + 2], s3 = idxd[i + 3];
            float v0 = proj[(size_t)s0 * 192 + 64 + lane];
            float v1 = proj[(size_t)s1 * 192 + 64 + lane];
            float v2 = proj[(size_t)s2 * 192 + 64 + lane];
            float v3 = proj[(size_t)s3 * 192 + 64 + lane];
            ad += (v0 + v1) + (v2 + v3);
        }
        for (; i < e; ++i) ad += proj[(size_t)idxd[i] * 192 + 64 + lane];
    }
    au *= invu[n];
    ad *= invd[n];
    float bi = proj[(size_t)n * 192 + 128 + lane];
    float ss = au * au + ad * ad + bi * bi;
#pragma unroll
    for (int off = 32; off; off >>= 1) ss += __shfl_xor(ss, off);
    float r = 1.0f / fmaxf(sqrtf(ss), 1e-12f);
    au *= r; ad *= r; bi *= r;
    au = au >= 0.f ? au : 0.1f * au;
    ad = ad >= 0.f ? ad : 0.1f * ad;
    bi = bi >= 0.f ? bi : 0.1f * bi;
    h[(size_t)n * 192 + lane] = au;
    h[(size_t)n * 192 + 64 + lane] = ad;
    h[(size_t)n * 192 + 128 + lane] = bi;
}

// ---------------- decoder ----------------
__global__ __launch_bounds__(128) void m1_kernel(const float* __restrict__ P1,
                                                 const float* __restrict__ P2,
                                                 float* __restrict__ tmpM) {
    int i = blockIdx.x, c = threadIdx.x;
    float s = 0.f;
    for (int k = 0; k < 128; ++k) s += P1[i * 128 + k] * P2[k * 128 + c];
    tmpM[i * 128 + c] = s;
}

__global__ __launch_bounds__(192) void m2_kernel(const float* __restrict__ tmpM,
                                                 const float* __restrict__ P1,
                                                 float* __restrict__ M) {
    __shared__ float trow[128];
    int i = blockIdx.x, j = threadIdx.x;
    if (j < 128) trow[j] = tmpM[i * 128 + j];
    __syncthreads();
    float s = 0.f;
    for (int k = 0; k < 128; ++k) s += trow[k] * P1[j * 128 + k];
    M[i * 192 + j] = s;
}

__global__ __launch_bounds__(192) void decode_kernel(const float* __restrict__ h,
                                                     const int* __restrict__ di,
                                                     const float* __restrict__ M,
                                                     float* __restrict__ out) {
    __shared__ alignas(16) float bvs[8][192];
    __shared__ float red[3][8];
    int pb = blockIdx.x * 8;
    int i = threadIdx.x;
#pragma unroll
    for (int p = 0; p < 8; ++p) {
        int nb = di[(pb + p) * 2 + 1] - 1;
        bvs[p][i] = h[(size_t)nb * 192 + i];
    }
    __syncthreads();
    float t[8] = {};
    const float4* M4 = (const float4*)(M + (size_t)i * 192);
    for (int j4 = 0; j4 < 48; ++j4) {
        float4 m = M4[j4];
#pragma unroll
        for (int p = 0; p < 8; ++p) {
            float4 b = *(const float4*)&bvs[p][j4 * 4];
            t[p] += m.x * b.x + m.y * b.y + m.z * b.z + m.w * b.w;
        }
    }
    int wid = i >> 6, lane = i & 63;
#pragma unroll
    for (int p = 0; p < 8; ++p) {
        int na = di[(pb + p) * 2] - 1;
        float v = h[(size_t)na * 192 + i] * t[p];
#pragma unroll
        for (int off = 32; off; off >>= 1) v += __shfl_xor(v, off);
        if (lane == 0) red[wid][p] = v;
    }
    __syncthreads();
    if (i < 8) out[pb + i] = red[0][i] + red[1][i] + red[2][i];
}

extern "C" void kernel_launch(void* const* d_in, const int* in_sizes, int n_in,
                              void* d_out, int out_size, void* d_ws, size_t ws_size,
                              hipStream_t stream) {
    const float* x     = (const float*)d_in[0];
    const int*   ei    = (const int*)d_in[1];
    const int*   di    = (const int*)d_in[2];
    const float* gamma = (const float*)d_in[3];
    const float* beta  = (const float*)d_in[4];
    const float* Wu[3] = {(const float*)d_in[5], (const float*)d_in[8],  (const float*)d_in[11]};
    const float* Wd[3] = {(const float*)d_in[6], (const float*)d_in[9],  (const float*)d_in[12]};
    const float* Wb[3] = {(const float*)d_in[7], (const float*)d_in[10], (const float*)d_in[13]};
    const float* P1    = (const float*)d_in[14];
    const float* P2    = (const float*)d_in[15];
    float* out = (float*)d_out;
    float* ws  = (float*)d_ws;

    float* bn   = ws + OFF_BN;
    float* tmpM = ws + OFF_TMPM;
    float* M    = ws + OFF_M;
    float* invu = ws + OFF_INVU;
    float* invd = ws + OFF_INVD;
    int* degu = (int*)(ws + OFF_DEGU);
    int* degd = (int*)(ws + OFF_DEGD);
    int* curu = (int*)(ws + OFF_CURU);
    int* curd = (int*)(ws + OFF_CURD);
    int* offu = (int*)(ws + OFF_OFFU);
    int* offd = (int*)(ws + OFF_OFFD);
    int* idxu = (int*)(ws + OFF_IDXU);
    int* idxd = (int*)(ws + OFF_IDXD);
    float* h    = ws + OFF_H;
    float* proj = ws + OFF_PROJ;

    hipMemsetAsync(bn, 0, 128 * sizeof(float), stream);
    hipMemsetAsync(degu, 0, 4 * (size_t)PN * sizeof(int), stream);  // degu|degd|curu|curd

    bn_stats_kernel<<<200, 256, 0, stream>>>(x, bn, PN);
    bn_finalize_kernel<<<1, 64, 0, stream>>>(gamma, beta, bn, PN);
    apply_bn_kernel<<<(PN * 64 + 255) / 256, 256, 0, stream>>>(x, bn, h, PN);

    deg_kernel<<<(PE + 255) / 256, 256, 0, stream>>>(ei, degu, degd, PE);
    invdeg_kernel<<<(PN + 255) / 256, 256, 0, stream>>>(degu, degd, invu, invd, PN);
    scan_kernel<<<1, 1024, 0, stream>>>(degu, degd, offu, offd, PN);
    fill_kernel<<<(PE + 255) / 256, 256, 0, stream>>>(ei, offu, offd, curu, curd, idxu, idxd, PE);

    for (int l = 0; l < 3; ++l) {
        int K = (l == 0) ? 64 : 192;
        dim3 ggrid((PN + 63) / 64, 3);
        gemm_kernel<<<ggrid, 256, 0, stream>>>(h, Wu[l], Wd[l], Wb[l], proj, PN, K);
        gather_kernel<<<(PN + 3) / 4, 256, 0, stream>>>(proj, offu, idxu, offd, idxd,
                                                        invu, invd, h, PN);
    }

    m1_kernel<<<192, 128, 0, stream>>>(P1, P2, tmpM);
    m2_kernel<<<192, 192, 0, stream>>>(tmpM, P1, M);
    decode_kernel<<<PB / 8, 192, 0, stream>>>(h, di, M, out);
}

// Round 3
// 890.840 us; speedup vs baseline: 2.7728x; 1.3385x over previous
//
#include <hip/hip_runtime.h>

#define PN 50000
#define PE 1600000
#define PB 4096

typedef __attribute__((ext_vector_type(8))) short bf16x8;
typedef __attribute__((ext_vector_type(4))) float f32x4;

__device__ inline float b2f(ushort u) {
    union { unsigned int i; float f; } x; x.i = ((unsigned int)u) << 16; return x.f;
}
__device__ inline ushort f2b(float f) {
    union { float f; unsigned int i; } x; x.f = f;
    unsigned int r = (x.i + 0x7FFFu + ((x.i >> 16) & 1u)) >> 16;
    return (ushort)r;
}

// ---------------- workspace layout (in 4-byte words) ----------------
static constexpr size_t OFF_BN   = 0;                         // 256 f
static constexpr size_t OFF_TMPM = 256;                       // 192*128 f
static constexpr size_t OFF_M    = OFF_TMPM + 192 * 128;      // 192*192 f
static constexpr size_t OFF_INVU = OFF_M + 192 * 192;         // N f
static constexpr size_t OFF_INVD = OFF_INVU + PN;             // N f
static constexpr size_t OFF_DEGU = OFF_INVD + PN;             // N int (zeroed block of 4N)
static constexpr size_t OFF_DEGD = OFF_DEGU + PN;
static constexpr size_t OFF_CURU = OFF_DEGD + PN;
static constexpr size_t OFF_CURD = OFF_CURU + PN;
static constexpr size_t OFF_OFFU = OFF_CURD + PN;             // N+1 int
static constexpr size_t OFF_OFFD = OFF_OFFU + PN + 1;         // N+1 int
static constexpr size_t OFF_IDXU = ((OFF_OFFD + PN + 1 + 3) / 4) * 4;  // E int
static constexpr size_t OFF_IDXD = OFF_IDXU + PE;             // E int
static constexpr size_t OFF_WB16 = OFF_IDXD + PE;             // 43008 words (bf16 weights)
static constexpr size_t OFF_HB   = ((OFF_WB16 + 43008 + 3) / 4) * 4;   // N*192 bf16 = 4.8M words
static constexpr size_t OFF_PROJ = OFF_HB + (size_t)PN * 96;  // N*192 bf16

// ---------------- batchnorm ----------------
__global__ __launch_bounds__(256) void bn_stats_kernel(const float* __restrict__ x,
                                                       float* __restrict__ sums, int N) {
    __shared__ float ls[256], ls2[256];
    int col = threadIdx.x & 63;
    int rstart = blockIdx.x * 4 + (threadIdx.x >> 6);
    float s = 0.f, s2 = 0.f;
    for (int r = rstart; r < N; r += gridDim.x * 4) {
        float v = x[(size_t)r * 64 + col];
        s += v; s2 += v * v;
    }
    ls[threadIdx.x] = s; ls2[threadIdx.x] = s2;
    __syncthreads();
    if (threadIdx.x < 64) {
        s  = ls[threadIdx.x]  + ls[threadIdx.x + 64]  + ls[threadIdx.x + 128]  + ls[threadIdx.x + 192];
        s2 = ls2[threadIdx.x] + ls2[threadIdx.x + 64] + ls2[threadIdx.x + 128] + ls2[threadIdx.x + 192];
        atomicAdd(&sums[col], s);
        atomicAdd(&sums[64 + col], s2);
    }
}

__global__ __launch_bounds__(64) void bn_finalize_kernel(const float* __restrict__ gamma,
                                                         const float* __restrict__ beta,
                                                         float* __restrict__ bn, int N) {
    int c = threadIdx.x;
    float mean = bn[c] / (float)N;
    float var = bn[64 + c] / (float)N - mean * mean;
    float sc = gamma[c] * rsqrtf(var + 1e-5f);
    bn[128 + c] = sc;
    bn[192 + c] = beta[c] - mean * sc;
}

__global__ __launch_bounds__(256) void apply_bn_kernel(const float* __restrict__ x,
                                                       const float* __restrict__ bn,
                                                       ushort* __restrict__ hb, int N) {
    int idx = blockIdx.x * 256 + threadIdx.x;
    if (idx >= N * 64) return;
    int n = idx >> 6, f = idx & 63;
    hb[(size_t)n * 192 + f] = f2b(x[idx] * bn[128 + f] + bn[192 + f]);
}

// ---------------- CSR build ----------------
__global__ __launch_bounds__(256) void deg_kernel(const int* __restrict__ ei,
                                                  int* __restrict__ degu,
                                                  int* __restrict__ degd, int E) {
    int e = blockIdx.x * 256 + threadIdx.x;
    if (e >= E) return;
    atomicAdd(&degu[ei[E + e]], 1);
    atomicAdd(&degd[ei[e]], 1);
}

__global__ __launch_bounds__(256) void invdeg_kernel(const int* __restrict__ degu,
                                                     const int* __restrict__ degd,
                                                     float* __restrict__ invu,
                                                     float* __restrict__ invd, int N) {
    int i = blockIdx.x * 256 + threadIdx.x;
    if (i >= N) return;
    invu[i] = 1.0f / (float)max(degu[i], 1);
    invd[i] = 1.0f / (float)max(degd[i], 1);
}

__global__ __launch_bounds__(1024) void scan_kernel(const int* __restrict__ degu,
                                                    const int* __restrict__ degd,
                                                    int* __restrict__ offu,
                                                    int* __restrict__ offd, int N) {
    __shared__ int wsum[17];
    int tid = threadIdx.x, lane = tid & 63, wid = tid >> 6;
    for (int a = 0; a < 2; ++a) {
        const int* deg = a ? degd : degu;
        int* off = a ? offd : offu;
        int run = 0;
        for (int base = 0; base < N; base += 1024) {
            int idx = base + tid;
            int v = (idx < N) ? deg[idx] : 0;
            int inc = v;
#pragma unroll
            for (int d = 1; d < 64; d <<= 1) {
                int t = __shfl_up(inc, d);
                if (lane >= d) inc += t;
            }
            if (lane == 63) wsum[wid] = inc;
            __syncthreads();
            if (tid == 0) {
                int r2 = 0;
#pragma unroll
                for (int i = 0; i < 16; ++i) { int t = wsum[i]; wsum[i] = r2; r2 += t; }
                wsum[16] = r2;
            }
            __syncthreads();
            if (idx < N) off[idx] = run + wsum[wid] + inc - v;
            run += wsum[16];
            __syncthreads();
        }
        if (tid == 0) off[N] = run;
        __syncthreads();
    }
}

// XCD-partitioned fill: partition p = blockIdx.x & 7 handles dest nodes
// [p*6250, (p+1)*6250); round-robin blockIdx->XCD pins each partition's
// write region (~3.2 MB) into one XCD's L2 -> full write combining.
__global__ __launch_bounds__(256) void fill_kernel(const int* __restrict__ ei,
                                                   const int* __restrict__ offu,
                                                   const int* __restrict__ offd,
                                                   int* __restrict__ curu,
                                                   int* __restrict__ curd,
                                                   int* __restrict__ idxu,
                                                   int* __restrict__ idxd, int E) {
    const int part = blockIdx.x & 7;
    const int slice = blockIdx.x >> 3;          // 128 slices
    const int lo = part * (PN / 8);
    const int hi = lo + (PN / 8);
    const int per = (PE + 127) / 128;           // 12500
    const int start = slice * per;
    const int end = min(E, start + per);
    for (int e = start + threadIdx.x; e < end; e += 256) {
        int r = ei[e], c = ei[E + e];
        if (c >= lo && c < hi) {
            int p = atomicAdd(&curu[c], 1);
            idxu[offu[c] + p] = r;
        }
        if (r >= lo && r < hi) {
            int q = atomicAdd(&curd[r], 1);
            idxd[offd[r] + q] = c;
        }
    }
}

// ---------------- weight convert: out[c][k] (col-major, bf16), c: 0-63=Wu,64-127=Wd,128-191=Wb
template<int K>
__global__ __launch_bounds__(256) void wconv_kernel(const float* __restrict__ Wu,
                                                    const float* __restrict__ Wd,
                                                    const float* __restrict__ Wb,
                                                    ushort* __restrict__ out) {
    int idx = blockIdx.x * 256 + threadIdx.x;
    if (idx >= 192 * K) return;
    int c = idx / K, k = idx - c * K;
    const float* W = (c < 64) ? Wu : (c < 128 ? Wd : Wb);
    out[idx] = f2b(W[k * 64 + (c & 63)]);
}

// ---------------- MFMA GEMM: proj[N,192](bf16) = hb[N,K](bf16,ld192) @ W[K,192](bf16) ----------------
// 256 thr = 4 waves; block = 64 rows x 192 cols; W staged in LDS [col][K+8]
template<int K>
__global__ __launch_bounds__(256) void gemm_kernel(const ushort* __restrict__ hb,
                                                   const ushort* __restrict__ wb,
                                                   ushort* __restrict__ proj, int nrows) {
    constexpr int KP = K + 8;
    __shared__ ushort wlds[192 * KP];
    const int tid = threadIdx.x;
    constexpr int KB8 = K / 8;
    for (int idx = tid; idx < 192 * KB8; idx += 256) {
        int col = idx / KB8, kb = idx - col * KB8;
        *(bf16x8*)&wlds[col * KP + kb * 8] = *(const bf16x8*)&wb[(size_t)col * K + kb * 8];
    }
    __syncthreads();
    const int lane = tid & 63, wid = tid >> 6;
    const int row = blockIdx.x * 64 + wid * 16 + (lane & 15);
    const int arow = min(row, nrows - 1);
    const int kgrp = (lane >> 4) * 8;
    f32x4 acc[12];
#pragma unroll
    for (int i = 0; i < 12; ++i) acc[i] = (f32x4)0.0f;
    const ushort* aptr = hb + (size_t)arow * 192 + kgrp;
#pragma unroll
    for (int k0 = 0; k0 < K; k0 += 32) {
        bf16x8 af = *(const bf16x8*)(aptr + k0);
#pragma unroll
        for (int cb = 0; cb < 3; ++cb)
#pragma unroll
            for (int ct = 0; ct < 4; ++ct) {
                int col = cb * 64 + ct * 16 + (lane & 15);
                bf16x8 bfr = *(const bf16x8*)&wlds[col * KP + k0 + kgrp];
                acc[cb * 4 + ct] =
                    __builtin_amdgcn_mfma_f32_16x16x32_bf16(af, bfr, acc[cb * 4 + ct], 0, 0, 0);
            }
    }
    const int orow0 = blockIdx.x * 64 + wid * 16 + (lane >> 4) * 4;
#pragma unroll
    for (int cb = 0; cb < 3; ++cb)
#pragma unroll
        for (int ct = 0; ct < 4; ++ct) {
            int ocol = cb * 64 + ct * 16 + (lane & 15);
#pragma unroll
            for (int j = 0; j < 4; ++j) {
                int orow = orow0 + j;
                if (orow < nrows) proj[(size_t)orow * 192 + ocol] = f2b(acc[cb * 4 + ct][j]);
            }
        }
}

// ---------------- fused gather + divide + L2-normalize + leaky (bf16 in/out) ----------------
__global__ __launch_bounds__(256) void gather_kernel(const ushort* __restrict__ proj,
                                                     const int* __restrict__ offu,
                                                     const int* __restrict__ idxu,
                                                     const int* __restrict__ offd,
                                                     const int* __restrict__ idxd,
                                                     const float* __restrict__ invu,
                                                     const float* __restrict__ invd,
                                                     ushort* __restrict__ hb, int N) {
    int n = blockIdx.x * 4 + (threadIdx.x >> 6);
    int lane = threadIdx.x & 63;
    if (n >= N) return;
    float au = 0.f, ad = 0.f;
    {
        int s = offu[n], e = offu[n + 1], i = s;
        for (; i + 4 <= e; i += 4) {
            int s0 = idxu[i], s1 = idxu[i + 1], s2 = idxu[i + 2], s3 = idxu[i + 3];
            float v0 = b2f(proj[(size_t)s0 * 192 + lane]);
            float v1 = b2f(proj[(size_t)s1 * 192 + lane]);
            float v2 = b2f(proj[(size_t)s2 * 192 + lane]);
            float v3 = b2f(proj[(size_t)s3 * 192 + lane]);
            au += (v0 + v1) + (v2 + v3);
        }
        for (; i < e; ++i) au += b2f(proj[(size_t)idxu[i] * 192 + lane]);
    }
    {
        int s = offd[n], e = offd[n + 1], i = s;
        for (; i + 4 <= e; i += 4) {
            int s0 = idxd[i], s1 = idxd[i + 1], s2 = idxd[i + 2], s3 = idxd[i + 3];
            float v0 = b2f(proj[(size_t)s0 * 192 + 64 + lane]);
            float v1 = b2f(proj[(size_t)s1 * 192 + 64 + lane]);
            float v2 = b2f(proj[(size_t)s2 * 192 + 64 + lane]);
            float v3 = b2f(proj[(size_t)s3 * 192 + 64 + lane]);
            ad += (v0 + v1) + (v2 + v3);
        }
        for (; i < e; ++i) ad += b2f(proj[(size_t)idxd[i] * 192 + 64 + lane]);
    }
    au *= invu[n];
    ad *= invd[n];
    float bi = b2f(proj[(size_t)n * 192 + 128 + lane]);
    float ss = au * au + ad * ad + bi * bi;
#pragma unroll
    for (int off = 32; off; off >>= 1) ss += __shfl_xor(ss, off);
    float r = 1.0f / fmaxf(sqrtf(ss), 1e-12f);
    au *= r; ad *= r; bi *= r;
    au = au >= 0.f ? au : 0.1f * au;
    ad = ad >= 0.f ? ad : 0.1f * ad;
    bi = bi >= 0.f ? bi : 0.1f * bi;
    hb[(size_t)n * 192 + lane] = f2b(au);
    hb[(size_t)n * 192 + 64 + lane] = f2b(ad);
    hb[(size_t)n * 192 + 128 + lane] = f2b(bi);
}

// ---------------- decoder ----------------
__global__ __launch_bounds__(128) void m1_kernel(const float* __restrict__ P1,
                                                 const float* __restrict__ P2,
                                                 float* __restrict__ tmpM) {
    int i = blockIdx.x, c = threadIdx.x;
    float s = 0.f;
    for (int k = 0; k < 128; ++k) s += P1[i * 128 + k] * P2[k * 128 + c];
    tmpM[i * 128 + c] = s;
}

__global__ __launch_bounds__(192) void m2_kernel(const float* __restrict__ tmpM,
                                                 const float* __restrict__ P1,
                                                 float* __restrict__ M) {
    __shared__ float trow[128];
    int i = blockIdx.x, j = threadIdx.x;
    if (j < 128) trow[j] = tmpM[i * 128 + j];
    __syncthreads();
    float s = 0.f;
    for (int k = 0; k < 128; ++k) s += trow[k] * P1[j * 128 + k];
    M[i * 192 + j] = s;
}

__global__ __launch_bounds__(192) void decode_kernel(const ushort* __restrict__ hb,
                                                     const int* __restrict__ di,
                                                     const float* __restrict__ M,
                                                     float* __restrict__ out) {
    __shared__ alignas(16) float bvs[8][192];
    __shared__ float red[3][8];
    int pb = blockIdx.x * 8;
    int i = threadIdx.x;
#pragma unroll
    for (int p = 0; p < 8; ++p) {
        int nb = di[(pb + p) * 2 + 1] - 1;
        bvs[p][i] = b2f(hb[(size_t)nb * 192 + i]);
    }
    __syncthreads();
    float t[8] = {};
    const float4* M4 = (const float4*)(M + (size_t)i * 192);
    for (int j4 = 0; j4 < 48; ++j4) {
        float4 m = M4[j4];
#pragma unroll
        for (int p = 0; p < 8; ++p) {
            float4 b = *(const float4*)&bvs[p][j4 * 4];
            t[p] += m.x * b.x + m.y * b.y + m.z * b.z + m.w * b.w;
        }
    }
    int wid = i >> 6, lane = i & 63;
#pragma unroll
    for (int p = 0; p < 8; ++p) {
        int na = di[(pb + p) * 2] - 1;
        float v = b2f(hb[(size_t)na * 192 + i]) * t[p];
#pragma unroll
        for (int off = 32; off; off >>= 1) v += __shfl_xor(v, off);
        if (lane == 0) red[wid][p] = v;
    }
    __syncthreads();
    if (i < 8) out[pb + i] = red[0][i] + red[1][i] + red[2][i];
}

extern "C" void kernel_launch(void* const* d_in, const int* in_sizes, int n_in,
                              void* d_out, int out_size, void* d_ws, size_t ws_size,
                              hipStream_t stream) {
    const float* x     = (const float*)d_in[0];
    const int*   ei    = (const int*)d_in[1];
    const int*   di    = (const int*)d_in[2];
    const float* gamma = (const float*)d_in[3];
    const float* beta  = (const float*)d_in[4];
    const float* Wu[3] = {(const float*)d_in[5], (const float*)d_in[8],  (const float*)d_in[11]};
    const float* Wd[3] = {(const float*)d_in[6], (const float*)d_in[9],  (const float*)d_in[12]};
    const float* Wb[3] = {(const float*)d_in[7], (const float*)d_in[10], (const float*)d_in[13]};
    const float* P1    = (const float*)d_in[14];
    const float* P2    = (const float*)d_in[15];
    float* out = (float*)d_out;
    float* ws  = (float*)d_ws;

    float* bn   = ws + OFF_BN;
    float* tmpM = ws + OFF_TMPM;
    float* M    = ws + OFF_M;
    float* invu = ws + OFF_INVU;
    float* invd = ws + OFF_INVD;
    int* degu = (int*)(ws + OFF_DEGU);
    int* degd = (int*)(ws + OFF_DEGD);
    int* curu = (int*)(ws + OFF_CURU);
    int* curd = (int*)(ws + OFF_CURD);
    int* offu = (int*)(ws + OFF_OFFU);
    int* offd = (int*)(ws + OFF_OFFD);
    int* idxu = (int*)(ws + OFF_IDXU);
    int* idxd = (int*)(ws + OFF_IDXD);
    ushort* wb16 = (ushort*)(ws + OFF_WB16);
    ushort* hb   = (ushort*)(ws + OFF_HB);
    ushort* proj = (ushort*)(ws + OFF_PROJ);
    ushort* wbl[3] = {wb16, wb16 + 12288, wb16 + 49152};

    hipMemsetAsync(bn, 0, 128 * sizeof(float), stream);
    hipMemsetAsync(degu, 0, 4 * (size_t)PN * sizeof(int), stream);

    bn_stats_kernel<<<200, 256, 0, stream>>>(x, bn, PN);
    bn_finalize_kernel<<<1, 64, 0, stream>>>(gamma, beta, bn, PN);
    apply_bn_kernel<<<(PN * 64 + 255) / 256, 256, 0, stream>>>(x, bn, hb, PN);

    deg_kernel<<<(PE + 255) / 256, 256, 0, stream>>>(ei, degu, degd, PE);
    invdeg_kernel<<<(PN + 255) / 256, 256, 0, stream>>>(degu, degd, invu, invd, PN);
    scan_kernel<<<1, 1024, 0, stream>>>(degu, degd, offu, offd, PN);
    fill_kernel<<<8 * 128, 256, 0, stream>>>(ei, offu, offd, curu, curd, idxu, idxd, PE);

    wconv_kernel<64><<<(192 * 64 + 255) / 256, 256, 0, stream>>>(Wu[0], Wd[0], Wb[0], wbl[0]);
    wconv_kernel<192><<<(192 * 192 + 255) / 256, 256, 0, stream>>>(Wu[1], Wd[1], Wb[1], wbl[1]);
    wconv_kernel<192><<<(192 * 192 + 255) / 256, 256, 0, stream>>>(Wu[2], Wd[2], Wb[2], wbl[2]);

    const int ngb = (PN + 63) / 64;
    for (int l = 0; l < 3; ++l) {
        if (l == 0) gemm_kernel<64><<<ngb, 256, 0, stream>>>(hb, wbl[0], proj, PN);
        else        gemm_kernel<192><<<ngb, 256, 0, stream>>>(hb, wbl[l], proj, PN);
        gather_kernel<<<(PN + 3) / 4, 256, 0, stream>>>(proj, offu, idxu, offd, idxd,
                                                        invu, invd, hb, PN);
    }

    m1_kernel<<<192, 128, 0, stream>>>(P1, P2, tmpM);
    m2_kernel<<<192, 192, 0, stream>>>(tmpM, P1, M);
    decode_kernel<<<PB / 8, 192, 0, stream>>>(hb, di, M, out);
}